// Round 2
// baseline (3163.095 us; speedup 1.0000x reference)
//
#include <hip/hip_runtime.h>
#include <math.h>

// ---------------------------------------------------------------------------
// GCN 2-layer forward on MI355X (gfx950).
// Inputs: x[N,128] f32, edge_index[2,E] int32 (harness converts integer->int32),
//         W1[128,128], b1[128], W2[128,40], b2[40]
// Output: log_softmax over 40 classes, [N,40] f32.
// Round 1: fix edge_index dtype (int32, NOT int64 -- harness converts),
//          ws_size-adaptive feature chunking (FC in {128,64,32}),
//          fix k_lsm grid (one wave per node).
// ---------------------------------------------------------------------------

__global__ __launch_bounds__(256) void k_init_deg(int* __restrict__ deg, int N) {
    int i = blockIdx.x * 256 + threadIdx.x;
    if (i < N) deg[i] = 1;  // self loop
}

__global__ __launch_bounds__(256) void k_count(const int* __restrict__ row,
                                               int* __restrict__ deg, int E) {
    int i = blockIdx.x * 256 + threadIdx.x;
    if (i < E) atomicAdd(&deg[row[i]], 1);
}

__global__ __launch_bounds__(256) void k_dinv(const int* __restrict__ deg,
                                              float* __restrict__ dinv, int N) {
    int i = blockIdx.x * 256 + threadIdx.x;
    if (i < N) dinv[i] = rsqrtf((float)deg[i]);
}

// T[N,FC] = X[N,128] @ W1[:, f0:f0+FC]. 256 threads; each thread: 1 float4 col x 4 nodes.
template <int FC>
__global__ __launch_bounds__(256) void k_gemm1(const float* __restrict__ x,
                                               const float* __restrict__ W,
                                               float* __restrict__ T,
                                               int f0, int N) {
    constexpr int NQ = FC / 4;        // float4 columns
    constexpr int NB = 1024 / NQ;     // nodes per block
    constexpr int STEP = 256 / NQ;    // node-group stride
    __shared__ float Wl[128 * FC];
    __shared__ float xl[NB * 128];
    int t = threadIdx.x;

    float4* Wl4 = (float4*)Wl;
    const float4* W4 = (const float4*)W;  // [128 rows][32 float4]
#pragma unroll
    for (int i = 0; i < (128 * NQ) / 256; ++i) {
        int idx = t + 256 * i;
        int k = idx / NQ, j = idx % NQ;
        Wl4[idx] = W4[k * 32 + f0 / 4 + j];
    }
    long long nbase = (long long)blockIdx.x * NB;
    float4* xl4 = (float4*)xl;
    const float4* x4 = (const float4*)x;
#pragma unroll
    for (int i = 0; i < (NB * 32) / 256; ++i) {
        int idx = t + 256 * i;
        long long n = nbase + idx / 32;
        if (n >= N) n = N - 1;  // tail clamp (duplicate read, store is guarded)
        xl4[idx] = x4[n * 32 + (idx & 31)];
    }
    __syncthreads();

    int fq = t % NQ;
    int ng = t / NQ;
    float4 acc[4];
#pragma unroll
    for (int i = 0; i < 4; ++i) acc[i] = make_float4(0.f, 0.f, 0.f, 0.f);

#pragma unroll 8
    for (int k = 0; k < 128; ++k) {
        float4 w = Wl4[k * NQ + fq];
#pragma unroll
        for (int i = 0; i < 4; ++i) {
            float xv = xl[(ng + STEP * i) * 128 + k];
            acc[i].x = fmaf(xv, w.x, acc[i].x);
            acc[i].y = fmaf(xv, w.y, acc[i].y);
            acc[i].z = fmaf(xv, w.z, acc[i].z);
            acc[i].w = fmaf(xv, w.w, acc[i].w);
        }
    }
    float4* T4 = (float4*)T;
#pragma unroll
    for (int i = 0; i < 4; ++i) {
        long long n = nbase + ng + STEP * i;
        if (n < N) T4[n * NQ + fq] = acc[i];
    }
}

// U[n, f] = T[n, f] * dinv[n]^2  (self-loop term; initializes U)
template <int NQ>
__global__ __launch_bounds__(256) void k_self1(const float* __restrict__ T,
                                               const float* __restrict__ dinv,
                                               float* __restrict__ U, int N) {
    int i = blockIdx.x * 256 + threadIdx.x;  // over N*NQ float4
    if (i >= N * NQ) return;
    int n = i / NQ;
    float s = dinv[n];
    s = s * s;
    float4 v = ((const float4*)T)[i];
    v.x *= s; v.y *= s; v.z *= s; v.w *= s;
    ((float4*)U)[i] = v;
}

// push-scatter: NQ lanes per edge, float4 per lane, 4 fp32 atomics each
template <int NQ>
__global__ __launch_bounds__(256) void k_scat1(const int* __restrict__ ei,
                                               const float* __restrict__ T,
                                               const float* __restrict__ dinv,
                                               float* U, int E) {
    int tid = blockIdx.x * 256 + threadIdx.x;
    int e = tid / NQ;
    if (e >= E) return;
    int q = tid % NQ;
    int r = ei[e];
    int c = ei[E + e];
    float w = dinv[r] * dinv[c];
    float4 v = ((const float4*)(T + (long long)c * (NQ * 4)))[q];
    float* op = U + (long long)r * (NQ * 4) + q * 4;
    atomicAdd(op + 0, v.x * w);
    atomicAdd(op + 1, v.y * w);
    atomicAdd(op + 2, v.z * w);
    atomicAdd(op + 3, v.w * w);
}

template <int NQ>
__global__ __launch_bounds__(256) void k_relu(float* __restrict__ U,
                                              const float* __restrict__ b,
                                              int f0, int N) {
    int i = blockIdx.x * 256 + threadIdx.x;  // over N*NQ float4
    if (i >= N * NQ) return;
    int fq = i % NQ;
    float4 bv = ((const float4*)(b + f0))[fq];
    float4 v = ((float4*)U)[i];
    v.x = fmaxf(v.x + bv.x, 0.f);
    v.y = fmaxf(v.y + bv.y, 0.f);
    v.z = fmaxf(v.z + bv.z, 0.f);
    v.w = fmaxf(v.w + bv.w, 0.f);
    ((float4*)U)[i] = v;
}

// H2[N,40] (+)= U[N,FC] @ W2[f0:f0+FC, 40]. One thread: 2 nodes x 40 classes.
template <int FC>
__global__ __launch_bounds__(256) void k_gemm2(const float* __restrict__ h,
                                               const float* __restrict__ W2,
                                               float* __restrict__ H2,
                                               int f0, int N, int first) {
    __shared__ float Wl[FC * 40];
    int t = threadIdx.x;
    float4* Wl4 = (float4*)Wl;
    const float4* W4 = (const float4*)(W2 + (long long)f0 * 40);  // FC*10 float4, contiguous
    constexpr int WT = FC * 10;
#pragma unroll
    for (int i = 0; i < (WT + 255) / 256; ++i) {
        int idx = t + 256 * i;
        if (idx < WT) Wl4[idx] = W4[idx];
    }
    __syncthreads();

    int n0 = blockIdx.x * 512 + t;
    int n1 = n0 + 256;
    int n0c = n0 < N ? n0 : N - 1;
    int n1c = n1 < N ? n1 : N - 1;
    float a0[40], a1[40];
#pragma unroll
    for (int c = 0; c < 40; ++c) { a0[c] = 0.f; a1[c] = 0.f; }
    const float4* x0 = (const float4*)(h + (long long)n0c * FC);
    const float4* x1 = (const float4*)(h + (long long)n1c * FC);

    for (int k4 = 0; k4 < FC / 4; ++k4) {
        float4 xa = x0[k4];
        float4 xb = x1[k4];
#pragma unroll
        for (int j = 0; j < 4; ++j) {
            float xaj = ((const float*)&xa)[j];
            float xbj = ((const float*)&xb)[j];
            int k = k4 * 4 + j;
#pragma unroll
            for (int cq = 0; cq < 10; ++cq) {
                float4 w = Wl4[k * 10 + cq];
                a0[cq * 4 + 0] = fmaf(xaj, w.x, a0[cq * 4 + 0]);
                a0[cq * 4 + 1] = fmaf(xaj, w.y, a0[cq * 4 + 1]);
                a0[cq * 4 + 2] = fmaf(xaj, w.z, a0[cq * 4 + 2]);
                a0[cq * 4 + 3] = fmaf(xaj, w.w, a0[cq * 4 + 3]);
                a1[cq * 4 + 0] = fmaf(xbj, w.x, a1[cq * 4 + 0]);
                a1[cq * 4 + 1] = fmaf(xbj, w.y, a1[cq * 4 + 1]);
                a1[cq * 4 + 2] = fmaf(xbj, w.z, a1[cq * 4 + 2]);
                a1[cq * 4 + 3] = fmaf(xbj, w.w, a1[cq * 4 + 3]);
            }
        }
    }
    if (n0 < N) {
        float4* o = (float4*)(H2 + (long long)n0 * 40);
#pragma unroll
        for (int cq = 0; cq < 10; ++cq) {
            float4 r = make_float4(a0[cq*4+0], a0[cq*4+1], a0[cq*4+2], a0[cq*4+3]);
            if (!first) { float4 p = o[cq]; r.x += p.x; r.y += p.y; r.z += p.z; r.w += p.w; }
            o[cq] = r;
        }
    }
    if (n1 < N) {
        float4* o = (float4*)(H2 + (long long)n1 * 40);
#pragma unroll
        for (int cq = 0; cq < 10; ++cq) {
            float4 r = make_float4(a1[cq*4+0], a1[cq*4+1], a1[cq*4+2], a1[cq*4+3]);
            if (!first) { float4 p = o[cq]; r.x += p.x; r.y += p.y; r.z += p.z; r.w += p.w; }
            o[cq] = r;
        }
    }
}

// out[n,c] = H2[n,c] * dinv[n]^2 (self loop, initializes d_out)
__global__ __launch_bounds__(256) void k_self2(const float* __restrict__ H2,
                                               const float* __restrict__ dinv,
                                               float* __restrict__ out, int N) {
    int i = blockIdx.x * 256 + threadIdx.x;  // over N*40
    if (i >= N * 40) return;
    int n = i / 40;
    float s = dinv[n];
    out[i] = H2[i] * s * s;
}

// push-scatter layer 2: one thread per (edge, class)
__global__ __launch_bounds__(256) void k_scat2(const int* __restrict__ ei,
                                               const float* __restrict__ H2,
                                               const float* __restrict__ dinv,
                                               float* out, int E) {
    int tid = blockIdx.x * 256 + threadIdx.x;
    if (tid >= E * 40) return;
    int e = tid / 40;
    int c = tid % 40;
    int r = ei[e];
    int cc = ei[E + e];
    float w = dinv[r] * dinv[cc];
    atomicAdd(out + (long long)r * 40 + c, H2[(long long)cc * 40 + c] * w);
}

// in-place log_softmax over 40 classes; one wave per node, lanes 0..39 active
__global__ __launch_bounds__(256) void k_lsm(float* __restrict__ out,
                                             const float* __restrict__ b, int N) {
    int wid = (blockIdx.x * 256 + threadIdx.x) >> 6;
    int lane = threadIdx.x & 63;
    if (wid >= N) return;
    float v = -INFINITY;
    if (lane < 40) v = out[(long long)wid * 40 + lane] + b[lane];
    float m = v;
#pragma unroll
    for (int o = 32; o > 0; o >>= 1) m = fmaxf(m, __shfl_xor(m, o));
    float e = (lane < 40) ? expf(v - m) : 0.f;
    float s = e;
#pragma unroll
    for (int o = 32; o > 0; o >>= 1) s += __shfl_xor(s, o);
    if (lane < 40) out[(long long)wid * 40 + lane] = v - m - logf(s);
}

template <int FC>
static void run_all(const float* x, const int* ei, const float* W1, const float* b1,
                    const float* W2, const float* b2, float* out,
                    char* ws, int N, int E, hipStream_t stream) {
    constexpr int NQ = FC / 4;
    constexpr int NB = 1024 / NQ;
    int* deg = (int*)ws;                                   // N ints
    float* dinv = (float*)(ws + 512 * 1024);               // N floats
    float* H2 = (float*)(ws + 1024 * 1024);                // N*40 f32 = 16 MB
    char* tbase = ws + 17825792ULL;                        // 17 MB mark
    float* T = (float*)tbase;                              // N*FC f32
    float* U = (float*)(tbase + (size_t)N * FC * 4);       // N*FC f32

    k_init_deg<<<(N + 255) / 256, 256, 0, stream>>>(deg, N);
    k_count<<<(E + 255) / 256, 256, 0, stream>>>(ei, deg, E);
    k_dinv<<<(N + 255) / 256, 256, 0, stream>>>(deg, dinv, N);

    for (int c = 0; c < 128 / FC; ++c) {
        int f0 = c * FC;
        k_gemm1<FC><<<(N + NB - 1) / NB, 256, 0, stream>>>(x, W1, T, f0, N);
        k_self1<NQ><<<(N * NQ + 255) / 256, 256, 0, stream>>>(T, dinv, U, N);
        k_scat1<NQ><<<((long long)E * NQ + 255) / 256, 256, 0, stream>>>(ei, T, dinv, U, E);
        k_relu<NQ><<<(N * NQ + 255) / 256, 256, 0, stream>>>(U, b1, f0, N);
        k_gemm2<FC><<<(N + 511) / 512, 256, 0, stream>>>(U, W2, H2, f0, N, c == 0);
    }

    k_self2<<<(N * 40 + 255) / 256, 256, 0, stream>>>(H2, dinv, out, N);
    k_scat2<<<((long long)E * 40 + 255) / 256, 256, 0, stream>>>(ei, H2, dinv, out, E);
    k_lsm<<<((long long)N * 64 + 255) / 256, 256, 0, stream>>>(out, b2, N);
}

extern "C" void kernel_launch(void* const* d_in, const int* in_sizes, int n_in,
                              void* d_out, int out_size, void* d_ws, size_t ws_size,
                              hipStream_t stream) {
    const float* x  = (const float*)d_in[0];
    const int*   ei = (const int*)d_in[1];   // harness passes integer inputs as int32
    const float* W1 = (const float*)d_in[2];
    const float* b1 = (const float*)d_in[3];
    const float* W2 = (const float*)d_in[4];
    const float* b2 = (const float*)d_in[5];
    float* out = (float*)d_out;

    const int N = in_sizes[0] / 128;  // 100000
    const int E = in_sizes[1] / 2;    // 1600000

    // workspace need: 17 MB header (deg/dinv/H2) + 2 * N*FC*4
    size_t base = 17825792ULL;
    size_t need128 = base + 2ULL * N * 128 * 4;  // ~120 MB
    size_t need64  = base + 2ULL * N * 64 * 4;   // ~69 MB
    char* ws = (char*)d_ws;

    if (ws_size >= need128)
        run_all<128>(x, ei, W1, b1, W2, b2, out, ws, N, E, stream);
    else if (ws_size >= need64)
        run_all<64>(x, ei, W1, b1, W2, b2, out, ws, N, E, stream);
    else
        run_all<32>(x, ei, W1, b1, W2, b2, out, ws, N, E, stream);
}

// Round 3
// 476.184 us; speedup vs baseline: 6.6426x; 6.6426x over previous
//
#include <hip/hip_runtime.h>
#include <math.h>

// ---------------------------------------------------------------------------
// GCN 2-layer forward on MI355X (gfx950).
// Inputs: x[N,128] f32, edge_index[2,E] int32, W1[128,128], b1[128],
//         W2[128,40], b2[40].  Output: log_softmax [N,40] f32.
// Round 3: CSR build + pull-based aggregation (no fp32 atomics).
//   - deg/dinv as before; exclusive scan (2-level) -> row_ptr; scatter -> ecol/ewgt
//   - k_pull1 fuses self-loop + aggregate + bias + ReLU
//   - k_pull2 fuses self-loop + aggregate + bias + log_softmax
//   - FC=128 path aliases H2 onto T (dead after pull1): need 119.2MB < proven 120.2MB
// ---------------------------------------------------------------------------

__global__ __launch_bounds__(256) void k_init_deg(int* __restrict__ deg, int N) {
    int i = blockIdx.x * 256 + threadIdx.x;
    if (i < N) deg[i] = 1;  // self loop
}

__global__ __launch_bounds__(256) void k_count(const int* __restrict__ row,
                                               int* __restrict__ deg, int E) {
    int i = blockIdx.x * 256 + threadIdx.x;
    if (i < E) atomicAdd(&deg[row[i]], 1);
}

__global__ __launch_bounds__(256) void k_dinv(const int* __restrict__ deg,
                                              float* __restrict__ dinv, int N) {
    int i = blockIdx.x * 256 + threadIdx.x;
    if (i < N) dinv[i] = rsqrtf((float)deg[i]);
}

// block-level inclusive scan of (deg-1); partials to bsum
__global__ __launch_bounds__(256) void k_scan1(const int* __restrict__ deg,
                                               int* __restrict__ tmp,
                                               int* __restrict__ bsum, int N) {
    __shared__ int l[256];
    int t = threadIdx.x;
    int i = blockIdx.x * 256 + t;
    l[t] = (i < N) ? deg[i] - 1 : 0;
    __syncthreads();
#pragma unroll
    for (int o = 1; o < 256; o <<= 1) {
        int u = (t >= o) ? l[t - o] : 0;
        __syncthreads();
        l[t] += u;
        __syncthreads();
    }
    if (i < N) tmp[i] = l[t];
    if (t == 255) bsum[blockIdx.x] = l[255];
}

// inclusive scan of block partials (nb <= 1024)
__global__ __launch_bounds__(1024) void k_scan2(int* __restrict__ bsum, int nb) {
    __shared__ int l[1024];
    int t = threadIdx.x;
    l[t] = (t < nb) ? bsum[t] : 0;
    __syncthreads();
#pragma unroll
    for (int o = 1; o < 1024; o <<= 1) {
        int u = (t >= o) ? l[t - o] : 0;
        __syncthreads();
        l[t] += u;
        __syncthreads();
    }
    if (t < nb) bsum[t] = l[t];
}

// row_ptr = exclusive scan; cursor = copy; row_ptr[N] = E
__global__ __launch_bounds__(256) void k_scan3(const int* __restrict__ deg,
                                               const int* __restrict__ tmp,
                                               const int* __restrict__ bsum,
                                               int* __restrict__ row_ptr,
                                               int* __restrict__ cursor, int N, int E) {
    int i = blockIdx.x * 256 + threadIdx.x;
    if (i >= N) return;
    int excl = tmp[i] - (deg[i] - 1) + (blockIdx.x ? bsum[blockIdx.x - 1] : 0);
    row_ptr[i] = excl;
    cursor[i] = excl;
    if (i == 0) row_ptr[N] = E;
}

// scatter edges into CSR buckets; precompute edge weight
__global__ __launch_bounds__(256) void k_csr(const int* __restrict__ ei,
                                             const float* __restrict__ dinv,
                                             int* __restrict__ cursor,
                                             int* __restrict__ ecol,
                                             float* __restrict__ ewgt, int E) {
    int i = blockIdx.x * 256 + threadIdx.x;
    if (i >= E) return;
    int r = ei[i];
    int c = ei[E + i];
    int pos = atomicAdd(&cursor[r], 1);
    ecol[pos] = c;
    ewgt[pos] = dinv[r] * dinv[c];
}

// T[N,FC] = X[N,128] @ W1[:, f0:f0+FC]
template <int FC>
__global__ __launch_bounds__(256) void k_gemm1(const float* __restrict__ x,
                                               const float* __restrict__ W,
                                               float* __restrict__ T,
                                               int f0, int N) {
    constexpr int NQ = FC / 4;
    constexpr int NB = 1024 / NQ;
    constexpr int STEP = 256 / NQ;
    __shared__ float Wl[128 * FC];
    __shared__ float xl[NB * 128];
    int t = threadIdx.x;

    float4* Wl4 = (float4*)Wl;
    const float4* W4 = (const float4*)W;
#pragma unroll
    for (int i = 0; i < (128 * NQ) / 256; ++i) {
        int idx = t + 256 * i;
        int k = idx / NQ, j = idx % NQ;
        Wl4[idx] = W4[k * 32 + f0 / 4 + j];
    }
    long long nbase = (long long)blockIdx.x * NB;
    float4* xl4 = (float4*)xl;
    const float4* x4 = (const float4*)x;
#pragma unroll
    for (int i = 0; i < (NB * 32) / 256; ++i) {
        int idx = t + 256 * i;
        long long n = nbase + idx / 32;
        if (n >= N) n = N - 1;
        xl4[idx] = x4[n * 32 + (idx & 31)];
    }
    __syncthreads();

    int fq = t % NQ;
    int ng = t / NQ;
    float4 acc[4];
#pragma unroll
    for (int i = 0; i < 4; ++i) acc[i] = make_float4(0.f, 0.f, 0.f, 0.f);

#pragma unroll 8
    for (int k = 0; k < 128; ++k) {
        float4 w = Wl4[k * NQ + fq];
#pragma unroll
        for (int i = 0; i < 4; ++i) {
            float xv = xl[(ng + STEP * i) * 128 + k];
            acc[i].x = fmaf(xv, w.x, acc[i].x);
            acc[i].y = fmaf(xv, w.y, acc[i].y);
            acc[i].z = fmaf(xv, w.z, acc[i].z);
            acc[i].w = fmaf(xv, w.w, acc[i].w);
        }
    }
    float4* T4 = (float4*)T;
#pragma unroll
    for (int i = 0; i < 4; ++i) {
        long long n = nbase + ng + STEP * i;
        if (n < N) T4[n * NQ + fq] = acc[i];
    }
}

// U[n] = relu( dinv[n]^2*T[n] + sum_e w_e*T[col_e] + b )   (NQ float4 per node)
template <int NQ>
__global__ __launch_bounds__(256) void k_pull1(const float* __restrict__ T,
                                               const float* __restrict__ dinv,
                                               const int* __restrict__ row_ptr,
                                               const int* __restrict__ ecol,
                                               const float* __restrict__ ewgt,
                                               const float* __restrict__ b,
                                               int f0, float* __restrict__ U, int N) {
    int tid = blockIdx.x * 256 + threadIdx.x;
    int n = tid / NQ;
    if (n >= N) return;
    int q = tid % NQ;
    const float4* T4 = (const float4*)T;

    float s = dinv[n];
    float ss = s * s;
    float4 a = T4[(long long)n * NQ + q];
    a.x *= ss; a.y *= ss; a.z *= ss; a.w *= ss;

    int beg = row_ptr[n], end = row_ptr[n + 1];
    for (int i = beg; i < end; ++i) {
        int c = ecol[i];
        float w = ewgt[i];
        float4 v = T4[(long long)c * NQ + q];
        a.x = fmaf(w, v.x, a.x);
        a.y = fmaf(w, v.y, a.y);
        a.z = fmaf(w, v.z, a.z);
        a.w = fmaf(w, v.w, a.w);
    }
    float4 bv = ((const float4*)(b + f0))[q];
    a.x = fmaxf(a.x + bv.x, 0.f);
    a.y = fmaxf(a.y + bv.y, 0.f);
    a.z = fmaxf(a.z + bv.z, 0.f);
    a.w = fmaxf(a.w + bv.w, 0.f);
    ((float4*)U)[(long long)n * NQ + q] = a;
}

// H2[N,40] (+)= U[N,FC] @ W2[f0:f0+FC, 40]
template <int FC>
__global__ __launch_bounds__(256) void k_gemm2(const float* __restrict__ h,
                                               const float* __restrict__ W2,
                                               float* __restrict__ H2,
                                               int f0, int N, int first) {
    __shared__ float Wl[FC * 40];
    int t = threadIdx.x;
    float4* Wl4 = (float4*)Wl;
    const float4* W4 = (const float4*)(W2 + (long long)f0 * 40);
    constexpr int WT = FC * 10;
#pragma unroll
    for (int i = 0; i < (WT + 255) / 256; ++i) {
        int idx = t + 256 * i;
        if (idx < WT) Wl4[idx] = W4[idx];
    }
    __syncthreads();

    int n0 = blockIdx.x * 512 + t;
    int n1 = n0 + 256;
    int n0c = n0 < N ? n0 : N - 1;
    int n1c = n1 < N ? n1 : N - 1;
    float a0[40], a1[40];
#pragma unroll
    for (int c = 0; c < 40; ++c) { a0[c] = 0.f; a1[c] = 0.f; }
    const float4* x0 = (const float4*)(h + (long long)n0c * FC);
    const float4* x1 = (const float4*)(h + (long long)n1c * FC);

    for (int k4 = 0; k4 < FC / 4; ++k4) {
        float4 xa = x0[k4];
        float4 xb = x1[k4];
#pragma unroll
        for (int j = 0; j < 4; ++j) {
            float xaj = ((const float*)&xa)[j];
            float xbj = ((const float*)&xb)[j];
            int k = k4 * 4 + j;
#pragma unroll
            for (int cq = 0; cq < 10; ++cq) {
                float4 w = Wl4[k * 10 + cq];
                a0[cq * 4 + 0] = fmaf(xaj, w.x, a0[cq * 4 + 0]);
                a0[cq * 4 + 1] = fmaf(xaj, w.y, a0[cq * 4 + 1]);
                a0[cq * 4 + 2] = fmaf(xaj, w.z, a0[cq * 4 + 2]);
                a0[cq * 4 + 3] = fmaf(xaj, w.w, a0[cq * 4 + 3]);
                a1[cq * 4 + 0] = fmaf(xbj, w.x, a1[cq * 4 + 0]);
                a1[cq * 4 + 1] = fmaf(xbj, w.y, a1[cq * 4 + 1]);
                a1[cq * 4 + 2] = fmaf(xbj, w.z, a1[cq * 4 + 2]);
                a1[cq * 4 + 3] = fmaf(xbj, w.w, a1[cq * 4 + 3]);
            }
        }
    }
    if (n0 < N) {
        float4* o = (float4*)(H2 + (long long)n0 * 40);
#pragma unroll
        for (int cq = 0; cq < 10; ++cq) {
            float4 r = make_float4(a0[cq*4+0], a0[cq*4+1], a0[cq*4+2], a0[cq*4+3]);
            if (!first) { float4 p = o[cq]; r.x += p.x; r.y += p.y; r.z += p.z; r.w += p.w; }
            o[cq] = r;
        }
    }
    if (n1 < N) {
        float4* o = (float4*)(H2 + (long long)n1 * 40);
#pragma unroll
        for (int cq = 0; cq < 10; ++cq) {
            float4 r = make_float4(a1[cq*4+0], a1[cq*4+1], a1[cq*4+2], a1[cq*4+3]);
            if (!first) { float4 p = o[cq]; r.x += p.x; r.y += p.y; r.z += p.z; r.w += p.w; }
            o[cq] = r;
        }
    }
}

// out[n] = log_softmax( dinv^2*H2[n] + sum w*H2[c] + b2 )
// 16 threads per node, lanes q<10 hold one float4 each (40 classes)
__global__ __launch_bounds__(256) void k_pull2(const float* __restrict__ H2,
                                               const float* __restrict__ dinv,
                                               const int* __restrict__ row_ptr,
                                               const int* __restrict__ ecol,
                                               const float* __restrict__ ewgt,
                                               const float* __restrict__ b2,
                                               float* __restrict__ out, int N) {
    int tid = blockIdx.x * 256 + threadIdx.x;
    int n = tid >> 4;
    if (n >= N) return;
    int q = tid & 15;
    bool act = q < 10;
    const float4* H4 = (const float4*)H2;

    float s = dinv[n];
    float ss = s * s;
    float4 a = make_float4(0.f, 0.f, 0.f, 0.f);
    if (act) {
        a = H4[(long long)n * 10 + q];
        a.x *= ss; a.y *= ss; a.z *= ss; a.w *= ss;
    }
    int beg = row_ptr[n], end = row_ptr[n + 1];
    for (int i = beg; i < end; ++i) {
        int c = ecol[i];
        float w = ewgt[i];
        if (act) {
            float4 v = H4[(long long)c * 10 + q];
            a.x = fmaf(w, v.x, a.x);
            a.y = fmaf(w, v.y, a.y);
            a.z = fmaf(w, v.z, a.z);
            a.w = fmaf(w, v.w, a.w);
        }
    }
    if (act) {
        float4 bv = ((const float4*)b2)[q];
        a.x += bv.x; a.y += bv.y; a.z += bv.z; a.w += bv.w;
    }
    // group log-softmax over 16 lanes (10 active x 4 = 40 values)
    float m = act ? fmaxf(fmaxf(a.x, a.y), fmaxf(a.z, a.w)) : -INFINITY;
#pragma unroll
    for (int o = 8; o > 0; o >>= 1) m = fmaxf(m, __shfl_xor(m, o, 16));
    float e = act ? (expf(a.x - m) + expf(a.y - m) + expf(a.z - m) + expf(a.w - m)) : 0.f;
#pragma unroll
    for (int o = 8; o > 0; o >>= 1) e += __shfl_xor(e, o, 16);
    float lg = m + logf(e);
    if (act) {
        float4 r = make_float4(a.x - lg, a.y - lg, a.z - lg, a.w - lg);
        ((float4*)out)[(long long)n * 10 + q] = r;
    }
}

template <int FC>
static void run_all(const float* x, const int* ei, const float* W1, const float* b1,
                    const float* W2, const float* b2, float* out,
                    char* ws, int N, int E, hipStream_t stream) {
    constexpr int NQ = FC / 4;
    constexpr int NB = 1024 / NQ;

    // header layout (16 MB)
    int*   deg     = (int*)(ws);
    float* dinv    = (float*)(ws + (512 << 10));
    int*   row_ptr = (int*)(ws + (1 << 20));        // N+1
    int*   cursor  = (int*)(ws + (1536 << 10));
    int*   bsum    = (int*)(ws + (2 << 20));        // <=1024 ints
    int*   tmp     = (int*)(ws + (2 << 20) + (64 << 10));
    int*   ecol    = (int*)(ws + (3 << 20));        // E ints (6.4 MB)
    float* ewgt    = (float*)(ws + (3 << 20) + 6553600ULL);
    char*  tbase   = ws + (16 << 20);
    float* T  = (float*)tbase;
    float* U  = (float*)(tbase + (size_t)N * FC * 4);
    // FC==128: H2 aliases T (T dead after last pull1; single chunk)
    float* H2 = (FC == 128) ? (float*)tbase : (float*)(tbase + 2ULL * N * FC * 4);

    int nb = (N + 255) / 256;

    k_init_deg<<<nb, 256, 0, stream>>>(deg, N);
    k_count<<<(E + 255) / 256, 256, 0, stream>>>(ei, deg, E);
    k_dinv<<<nb, 256, 0, stream>>>(deg, dinv, N);

    k_scan1<<<nb, 256, 0, stream>>>(deg, tmp, bsum, N);
    k_scan2<<<1, 1024, 0, stream>>>(bsum, nb);
    k_scan3<<<nb, 256, 0, stream>>>(deg, tmp, bsum, row_ptr, cursor, N, E);
    k_csr<<<(E + 255) / 256, 256, 0, stream>>>(ei, dinv, cursor, ecol, ewgt, E);

    for (int c = 0; c < 128 / FC; ++c) {
        int f0 = c * FC;
        k_gemm1<FC><<<(N + NB - 1) / NB, 256, 0, stream>>>(x, W1, T, f0, N);
        k_pull1<NQ><<<((long long)N * NQ + 255) / 256, 256, 0, stream>>>(
            T, dinv, row_ptr, ecol, ewgt, b1, f0, U, N);
        k_gemm2<FC><<<(N + 511) / 512, 256, 0, stream>>>(U, W2, H2, f0, N, c == 0);
    }

    k_pull2<<<((long long)N * 16 + 255) / 256, 256, 0, stream>>>(
        H2, dinv, row_ptr, ecol, ewgt, b2, out, N);
}

extern "C" void kernel_launch(void* const* d_in, const int* in_sizes, int n_in,
                              void* d_out, int out_size, void* d_ws, size_t ws_size,
                              hipStream_t stream) {
    const float* x  = (const float*)d_in[0];
    const int*   ei = (const int*)d_in[1];   // integer inputs arrive as int32
    const float* W1 = (const float*)d_in[2];
    const float* b1 = (const float*)d_in[3];
    const float* W2 = (const float*)d_in[4];
    const float* b2 = (const float*)d_in[5];
    float* out = (float*)d_out;

    const int N = in_sizes[0] / 128;  // 100000
    const int E = in_sizes[1] / 2;    // 1600000

    size_t base = 16ULL << 20;
    size_t need128 = base + 2ULL * N * 128 * 4;              // H2 aliases T
    size_t need64  = base + (2ULL * N * 64 + N * 40) * 4;
    char* ws = (char*)d_ws;

    if (ws_size >= need128)
        run_all<128>(x, ei, W1, b1, W2, b2, out, ws, N, E, stream);
    else if (ws_size >= need64)
        run_all<64>(x, ei, W1, b1, W2, b2, out, ws, N, E, stream);
    else
        run_all<32>(x, ei, W1, b1, W2, b2, out, ws, N, E, stream);
}

// Round 4
// 372.331 us; speedup vs baseline: 8.4954x; 1.2789x over previous
//
#include <hip/hip_runtime.h>
#include <hip/hip_bf16.h>
#include <math.h>

// ---------------------------------------------------------------------------
// GCN 2-layer forward on MI355X (gfx950).
// Inputs: x[N,128] f32, edge_index[2,E] int32, W1[128,128], b1[128],
//         W2[128,40], b2[40].  Output: log_softmax [N,40] f32.
// Round 4: bf16 intermediates (T, U, H2) to halve gather traffic in the
//          pull kernels (k_pull1 was gather-BW bound: 406MB fetch, 3.65TB/s).
//          fp32 accumulation everywhere; single FC=128 path (~76MB ws).
// ---------------------------------------------------------------------------

struct f8 { float v[8]; };

__device__ inline f8 unpack8(uint4 u) {
    f8 r;
    r.v[0] = __uint_as_float(u.x << 16);
    r.v[1] = __uint_as_float(u.x & 0xffff0000u);
    r.v[2] = __uint_as_float(u.y << 16);
    r.v[3] = __uint_as_float(u.y & 0xffff0000u);
    r.v[4] = __uint_as_float(u.z << 16);
    r.v[5] = __uint_as_float(u.z & 0xffff0000u);
    r.v[6] = __uint_as_float(u.w << 16);
    r.v[7] = __uint_as_float(u.w & 0xffff0000u);
    return r;
}

__device__ inline unsigned pack2(float a, float b) {  // a -> low half (RNE)
    __hip_bfloat16 ha = __float2bfloat16(a);
    __hip_bfloat16 hb = __float2bfloat16(b);
    unsigned short sa = *(unsigned short*)&ha;
    unsigned short sb = *(unsigned short*)&hb;
    return (unsigned)sa | ((unsigned)sb << 16);
}

__global__ __launch_bounds__(256) void k_init_deg(int* __restrict__ deg, int N) {
    int i = blockIdx.x * 256 + threadIdx.x;
    if (i < N) deg[i] = 1;  // self loop
}

__global__ __launch_bounds__(256) void k_count(const int* __restrict__ row,
                                               int* __restrict__ deg, int E) {
    int i = blockIdx.x * 256 + threadIdx.x;
    if (i < E) atomicAdd(&deg[row[i]], 1);
}

// block-level inclusive scan of (deg-1); partials to bsum; also dinv = rsqrt(deg)
__global__ __launch_bounds__(256) void k_scan1(const int* __restrict__ deg,
                                               int* __restrict__ tmp,
                                               int* __restrict__ bsum,
                                               float* __restrict__ dinv, int N) {
    __shared__ int l[256];
    int t = threadIdx.x;
    int i = blockIdx.x * 256 + t;
    int d = (i < N) ? deg[i] : 1;
    if (i < N) dinv[i] = rsqrtf((float)d);
    l[t] = (i < N) ? d - 1 : 0;
    __syncthreads();
#pragma unroll
    for (int o = 1; o < 256; o <<= 1) {
        int u = (t >= o) ? l[t - o] : 0;
        __syncthreads();
        l[t] += u;
        __syncthreads();
    }
    if (i < N) tmp[i] = l[t];
    if (t == 255) bsum[blockIdx.x] = l[255];
}

__global__ __launch_bounds__(1024) void k_scan2(int* __restrict__ bsum, int nb) {
    __shared__ int l[1024];
    int t = threadIdx.x;
    l[t] = (t < nb) ? bsum[t] : 0;
    __syncthreads();
#pragma unroll
    for (int o = 1; o < 1024; o <<= 1) {
        int u = (t >= o) ? l[t - o] : 0;
        __syncthreads();
        l[t] += u;
        __syncthreads();
    }
    if (t < nb) bsum[t] = l[t];
}

__global__ __launch_bounds__(256) void k_scan3(const int* __restrict__ deg,
                                               const int* __restrict__ tmp,
                                               const int* __restrict__ bsum,
                                               int* __restrict__ row_ptr,
                                               int* __restrict__ cursor, int N, int E) {
    int i = blockIdx.x * 256 + threadIdx.x;
    if (i >= N) return;
    int excl = tmp[i] - (deg[i] - 1) + (blockIdx.x ? bsum[blockIdx.x - 1] : 0);
    row_ptr[i] = excl;
    cursor[i] = excl;
    if (i == 0) row_ptr[N] = E;
}

__global__ __launch_bounds__(256) void k_csr(const int* __restrict__ ei,
                                             const float* __restrict__ dinv,
                                             int* __restrict__ cursor,
                                             int* __restrict__ ecol,
                                             float* __restrict__ ewgt, int E) {
    int i = blockIdx.x * 256 + threadIdx.x;
    if (i >= E) return;
    int r = ei[i];
    int c = ei[E + i];
    int pos = atomicAdd(&cursor[r], 1);
    ecol[pos] = c;
    ewgt[pos] = dinv[r] * dinv[c];
}

// T[N,128](bf16) = X[N,128] @ W1. 32 nodes/block; thread: 4 nodes x 1 float4-col.
__global__ __launch_bounds__(256) void k_gemm1(const float* __restrict__ x,
                                               const float* __restrict__ W,
                                               unsigned* __restrict__ Tb, int N) {
    __shared__ float Wl[128 * 128];
    __shared__ float xl[32 * 128];
    int t = threadIdx.x;
    float4* Wl4 = (float4*)Wl;
    const float4* W4 = (const float4*)W;
#pragma unroll
    for (int i = 0; i < 16; ++i) Wl4[t + 256 * i] = W4[t + 256 * i];
    long long nbase = (long long)blockIdx.x * 32;
    float4* xl4 = (float4*)xl;
    const float4* x4 = (const float4*)x;
#pragma unroll
    for (int i = 0; i < 4; ++i) {
        int idx = t + 256 * i;
        long long n = nbase + idx / 32;
        if (n >= N) n = N - 1;
        xl4[idx] = x4[n * 32 + (idx & 31)];
    }
    __syncthreads();

    int fq = t & 31;   // float4 column
    int ng = t >> 5;   // 0..7 -> nodes ng, ng+8, ng+16, ng+24
    float4 acc[4];
#pragma unroll
    for (int i = 0; i < 4; ++i) acc[i] = make_float4(0.f, 0.f, 0.f, 0.f);

#pragma unroll 8
    for (int k = 0; k < 128; ++k) {
        float4 w = Wl4[k * 32 + fq];
#pragma unroll
        for (int i = 0; i < 4; ++i) {
            float xv = xl[(ng + 8 * i) * 128 + k];
            acc[i].x = fmaf(xv, w.x, acc[i].x);
            acc[i].y = fmaf(xv, w.y, acc[i].y);
            acc[i].z = fmaf(xv, w.z, acc[i].z);
            acc[i].w = fmaf(xv, w.w, acc[i].w);
        }
    }
    uint2* T2 = (uint2*)Tb;
#pragma unroll
    for (int i = 0; i < 4; ++i) {
        long long n = nbase + ng + 8 * i;
        if (n < N) {
            uint2 o;
            o.x = pack2(acc[i].x, acc[i].y);
            o.y = pack2(acc[i].z, acc[i].w);
            T2[n * 32 + fq] = o;
        }
    }
}

// U[n](bf16) = relu( dinv^2*T[n] + sum_e w_e*T[col_e] + b1 )
// 16 lanes/node, 8 bf16 features per lane (uint4).
__global__ __launch_bounds__(256) void k_pull1(const uint4* __restrict__ Tb,
                                               const float* __restrict__ dinv,
                                               const int* __restrict__ row_ptr,
                                               const int* __restrict__ ecol,
                                               const float* __restrict__ ewgt,
                                               const float* __restrict__ b,
                                               uint4* __restrict__ Ub, int N) {
    int tid = blockIdx.x * 256 + threadIdx.x;
    int n = tid >> 4;
    if (n >= N) return;
    int q = tid & 15;

    float ss = dinv[n];
    ss = ss * ss;
    f8 s8 = unpack8(Tb[(size_t)n * 16 + q]);
    float acc[8];
#pragma unroll
    for (int j = 0; j < 8; ++j) acc[j] = s8.v[j] * ss;

    int beg = row_ptr[n], end = row_ptr[n + 1];
    int i = beg;
    for (; i + 1 < end; i += 2) {
        int c0 = ecol[i], c1 = ecol[i + 1];
        float w0 = ewgt[i], w1 = ewgt[i + 1];
        uint4 g0 = Tb[(size_t)c0 * 16 + q];
        uint4 g1 = Tb[(size_t)c1 * 16 + q];
        f8 a0 = unpack8(g0);
        f8 a1 = unpack8(g1);
#pragma unroll
        for (int j = 0; j < 8; ++j) acc[j] = fmaf(w0, a0.v[j], acc[j]);
#pragma unroll
        for (int j = 0; j < 8; ++j) acc[j] = fmaf(w1, a1.v[j], acc[j]);
    }
    if (i < end) {
        int c0 = ecol[i];
        float w0 = ewgt[i];
        f8 a0 = unpack8(Tb[(size_t)c0 * 16 + q]);
#pragma unroll
        for (int j = 0; j < 8; ++j) acc[j] = fmaf(w0, a0.v[j], acc[j]);
    }

    float4 b0 = ((const float4*)b)[q * 2];
    float4 b1v = ((const float4*)b)[q * 2 + 1];
    acc[0] = fmaxf(acc[0] + b0.x, 0.f);
    acc[1] = fmaxf(acc[1] + b0.y, 0.f);
    acc[2] = fmaxf(acc[2] + b0.z, 0.f);
    acc[3] = fmaxf(acc[3] + b0.w, 0.f);
    acc[4] = fmaxf(acc[4] + b1v.x, 0.f);
    acc[5] = fmaxf(acc[5] + b1v.y, 0.f);
    acc[6] = fmaxf(acc[6] + b1v.z, 0.f);
    acc[7] = fmaxf(acc[7] + b1v.w, 0.f);

    uint4 o;
    o.x = pack2(acc[0], acc[1]);
    o.y = pack2(acc[2], acc[3]);
    o.z = pack2(acc[4], acc[5]);
    o.w = pack2(acc[6], acc[7]);
    Ub[(size_t)n * 16 + q] = o;
}

// H2[N,40](bf16) = U[N,128](bf16) @ W2[128,40]. One thread: 2 nodes x 40 classes.
__global__ __launch_bounds__(256) void k_gemm2(const uint4* __restrict__ Ub,
                                               const float* __restrict__ W2,
                                               uint4* __restrict__ H2b, int N) {
    __shared__ float Wl[128 * 40];
    int t = threadIdx.x;
    float4* Wl4 = (float4*)Wl;
    const float4* W4 = (const float4*)W2;
#pragma unroll
    for (int i = 0; i < 5; ++i) Wl4[t + 256 * i] = W4[t + 256 * i];
    __syncthreads();

    int n0 = blockIdx.x * 512 + t;
    int n1 = n0 + 256;
    int n0c = n0 < N ? n0 : N - 1;
    int n1c = n1 < N ? n1 : N - 1;
    float a0[40], a1[40];
#pragma unroll
    for (int c = 0; c < 40; ++c) { a0[c] = 0.f; a1[c] = 0.f; }

    for (int k8 = 0; k8 < 16; ++k8) {
        f8 xa = unpack8(Ub[(size_t)n0c * 16 + k8]);
        f8 xb = unpack8(Ub[(size_t)n1c * 16 + k8]);
#pragma unroll
        for (int j = 0; j < 8; ++j) {
            float xaj = xa.v[j];
            float xbj = xb.v[j];
            int k = k8 * 8 + j;
#pragma unroll
            for (int cq = 0; cq < 10; ++cq) {
                float4 w = Wl4[k * 10 + cq];
                a0[cq * 4 + 0] = fmaf(xaj, w.x, a0[cq * 4 + 0]);
                a0[cq * 4 + 1] = fmaf(xaj, w.y, a0[cq * 4 + 1]);
                a0[cq * 4 + 2] = fmaf(xaj, w.z, a0[cq * 4 + 2]);
                a0[cq * 4 + 3] = fmaf(xaj, w.w, a0[cq * 4 + 3]);
                a1[cq * 4 + 0] = fmaf(xbj, w.x, a1[cq * 4 + 0]);
                a1[cq * 4 + 1] = fmaf(xbj, w.y, a1[cq * 4 + 1]);
                a1[cq * 4 + 2] = fmaf(xbj, w.z, a1[cq * 4 + 2]);
                a1[cq * 4 + 3] = fmaf(xbj, w.w, a1[cq * 4 + 3]);
            }
        }
    }
    if (n0 < N) {
#pragma unroll
        for (int g = 0; g < 5; ++g) {
            uint4 o;
            o.x = pack2(a0[g * 8 + 0], a0[g * 8 + 1]);
            o.y = pack2(a0[g * 8 + 2], a0[g * 8 + 3]);
            o.z = pack2(a0[g * 8 + 4], a0[g * 8 + 5]);
            o.w = pack2(a0[g * 8 + 6], a0[g * 8 + 7]);
            H2b[(size_t)n0 * 5 + g] = o;
        }
    }
    if (n1 < N) {
#pragma unroll
        for (int g = 0; g < 5; ++g) {
            uint4 o;
            o.x = pack2(a1[g * 8 + 0], a1[g * 8 + 1]);
            o.y = pack2(a1[g * 8 + 2], a1[g * 8 + 3]);
            o.z = pack2(a1[g * 8 + 4], a1[g * 8 + 5]);
            o.w = pack2(a1[g * 8 + 6], a1[g * 8 + 7]);
            H2b[(size_t)n1 * 5 + g] = o;
        }
    }
}

// out[n] = log_softmax( dinv^2*H2[n] + sum w*H2[c] + b2 )  (f32 out)
// 8 lanes/node; lanes q<5 hold 8 classes each (uint4 of bf16).
__global__ __launch_bounds__(256) void k_pull2(const uint4* __restrict__ H2b,
                                               const float* __restrict__ dinv,
                                               const int* __restrict__ row_ptr,
                                               const int* __restrict__ ecol,
                                               const float* __restrict__ ewgt,
                                               const float* __restrict__ b2,
                                               float* __restrict__ out, int N) {
    int tid = blockIdx.x * 256 + threadIdx.x;
    int n = tid >> 3;
    if (n >= N) return;
    int q = tid & 7;
    bool act = q < 5;

    float ss = dinv[n];
    ss = ss * ss;
    float acc[8];
#pragma unroll
    for (int j = 0; j < 8; ++j) acc[j] = 0.f;
    if (act) {
        f8 s8 = unpack8(H2b[(size_t)n * 5 + q]);
#pragma unroll
        for (int j = 0; j < 8; ++j) acc[j] = s8.v[j] * ss;
    }
    int beg = row_ptr[n], end = row_ptr[n + 1];
    for (int i = beg; i < end; ++i) {
        if (act) {
            int c = ecol[i];
            float w = ewgt[i];
            f8 a = unpack8(H2b[(size_t)c * 5 + q]);
#pragma unroll
            for (int j = 0; j < 8; ++j) acc[j] = fmaf(w, a.v[j], acc[j]);
        }
    }
    if (act) {
        float4 b0 = ((const float4*)b2)[q * 2];
        float4 b1v = ((const float4*)b2)[q * 2 + 1];
        acc[0] += b0.x; acc[1] += b0.y; acc[2] += b0.z; acc[3] += b0.w;
        acc[4] += b1v.x; acc[5] += b1v.y; acc[6] += b1v.z; acc[7] += b1v.w;
    }
    float m = -INFINITY;
    if (act) {
#pragma unroll
        for (int j = 0; j < 8; ++j) m = fmaxf(m, acc[j]);
    }
#pragma unroll
    for (int o = 4; o > 0; o >>= 1) m = fmaxf(m, __shfl_xor(m, o, 8));
    float e = 0.f;
    if (act) {
#pragma unroll
        for (int j = 0; j < 8; ++j) e += expf(acc[j] - m);
    }
#pragma unroll
    for (int o = 4; o > 0; o >>= 1) e += __shfl_xor(e, o, 8);
    float lg = m + logf(e);
    if (act) {
        float4* o4 = (float4*)out;
        o4[(size_t)n * 10 + q * 2] =
            make_float4(acc[0] - lg, acc[1] - lg, acc[2] - lg, acc[3] - lg);
        o4[(size_t)n * 10 + q * 2 + 1] =
            make_float4(acc[4] - lg, acc[5] - lg, acc[6] - lg, acc[7] - lg);
    }
}

extern "C" void kernel_launch(void* const* d_in, const int* in_sizes, int n_in,
                              void* d_out, int out_size, void* d_ws, size_t ws_size,
                              hipStream_t stream) {
    const float* x  = (const float*)d_in[0];
    const int*   ei = (const int*)d_in[1];   // integer inputs arrive as int32
    const float* W1 = (const float*)d_in[2];
    const float* b1 = (const float*)d_in[3];
    const float* W2 = (const float*)d_in[4];
    const float* b2 = (const float*)d_in[5];
    float* out = (float*)d_out;

    const int N = in_sizes[0] / 128;  // 100000
    const int E = in_sizes[1] / 2;    // 1600000

    // workspace layout (~76 MB total; proven ws_size >= 120 MB on this harness)
    char* ws = (char*)d_ws;
    int*   deg     = (int*)(ws);                       // 0.4 MB
    float* dinv    = (float*)(ws + (512 << 10));
    int*   row_ptr = (int*)(ws + (1 << 20));           // N+1
    int*   cursor  = (int*)(ws + (1536 << 10));
    int*   bsum    = (int*)(ws + (2 << 20));           // <=1024 ints
    int*   tmp     = (int*)(ws + (2 << 20) + (128 << 10));
    int*   ecol    = (int*)(ws + (3 << 20));           // E ints, 6.4 MB
    float* ewgt    = (float*)(ws + (3 << 20) + 6553600ULL);  // 6.4 MB, ends ~15.9
    uint4* H2b     = (uint4*)(ws + (16 << 20));        // N*40 bf16 = 8 MB
    unsigned* Tb   = (unsigned*)(ws + (24 << 20));     // N*128 bf16 = 25.6 MB
    uint4* Ub      = (uint4*)(ws + (50 << 20));        // N*128 bf16 = 25.6 MB

    int nb = (N + 255) / 256;

    k_init_deg<<<nb, 256, 0, stream>>>(deg, N);
    k_count<<<(E + 255) / 256, 256, 0, stream>>>(ei, deg, E);
    k_scan1<<<nb, 256, 0, stream>>>(deg, tmp, bsum, dinv, N);
    k_scan2<<<1, 1024, 0, stream>>>(bsum, nb);
    k_scan3<<<nb, 256, 0, stream>>>(deg, tmp, bsum, row_ptr, cursor, N, E);
    k_csr<<<(E + 255) / 256, 256, 0, stream>>>(ei, dinv, cursor, ecol, ewgt, E);

    k_gemm1<<<(N + 31) / 32, 256, 0, stream>>>(x, W1, Tb, N);
    k_pull1<<<((long long)N * 16 + 255) / 256, 256, 0, stream>>>(
        (const uint4*)Tb, dinv, row_ptr, ecol, ewgt, b1, Ub, N);
    k_gemm2<<<(N + 511) / 512, 256, 0, stream>>>(Ub, W2, H2b, N);
    k_pull2<<<((long long)N * 8 + 255) / 256, 256, 0, stream>>>(
        H2b, dinv, row_ptr, ecol, ewgt, b2, out, N);
}

// Round 5
// 371.530 us; speedup vs baseline: 8.5137x; 1.0022x over previous
//
#include <hip/hip_runtime.h>
#include <hip/hip_bf16.h>
#include <math.h>

// ---------------------------------------------------------------------------
// GCN 2-layer forward on MI355X (gfx950).
// Inputs: x[N,128] f32, edge_index[2,E] int32, W1[128,128], b1[128],
//         W2[128,40], b2[40].  Output: log_softmax [N,40] f32.
// Round 5: k_csr was write-amplification bound (155MB HBM writes for 12.8MB
//          payload; random scatter split across 8 non-coherent XCD L2s).
//          Fix: XCD-routed scatter -- block class (blockIdx&7) == row-group
//          class ((row>>5)&7), so each CSR/cursor/deg line is written by ONE
//          XCD and evicts once. Payload packed as int2 (col, wgt).
// ---------------------------------------------------------------------------

#define RTILE 8192  // edges per routed tile (x8 class-blocks each)

struct f8 { float v[8]; };

__device__ inline f8 unpack8(uint4 u) {
    f8 r;
    r.v[0] = __uint_as_float(u.x << 16);
    r.v[1] = __uint_as_float(u.x & 0xffff0000u);
    r.v[2] = __uint_as_float(u.y << 16);
    r.v[3] = __uint_as_float(u.y & 0xffff0000u);
    r.v[4] = __uint_as_float(u.z << 16);
    r.v[5] = __uint_as_float(u.z & 0xffff0000u);
    r.v[6] = __uint_as_float(u.w << 16);
    r.v[7] = __uint_as_float(u.w & 0xffff0000u);
    return r;
}

__device__ inline unsigned pack2(float a, float b) {  // a -> low half (RNE)
    __hip_bfloat16 ha = __float2bfloat16(a);
    __hip_bfloat16 hb = __float2bfloat16(b);
    unsigned short sa = *(unsigned short*)&ha;
    unsigned short sb = *(unsigned short*)&hb;
    return (unsigned)sa | ((unsigned)sb << 16);
}

__global__ __launch_bounds__(256) void k_init_deg(int* __restrict__ deg, int N) {
    int i = blockIdx.x * 256 + threadIdx.x;
    if (i < N) deg[i] = 1;  // self loop
}

// XCD-routed degree count: block class (blockIdx&7) handles row-groups
// ((r>>5)&7)==class, so each deg[] line is atomically updated from one XCD.
__global__ __launch_bounds__(256) void k_count(const int* __restrict__ row,
                                               int* __restrict__ deg, int E) {
    int tile = blockIdx.x >> 3;
    int cls  = blockIdx.x & 7;
    int base = tile * RTILE;
    int lim  = min(base + RTILE, E);
    for (int i = base + threadIdx.x; i < lim; i += 256) {
        int r = row[i];
        if (((r >> 5) & 7) == cls) atomicAdd(&deg[r], 1);
    }
}

// block-level inclusive scan of (deg-1); partials to bsum; also dinv = rsqrt(deg)
__global__ __launch_bounds__(256) void k_scan1(const int* __restrict__ deg,
                                               int* __restrict__ tmp,
                                               int* __restrict__ bsum,
                                               float* __restrict__ dinv, int N) {
    __shared__ int l[256];
    int t = threadIdx.x;
    int i = blockIdx.x * 256 + t;
    int d = (i < N) ? deg[i] : 1;
    if (i < N) dinv[i] = rsqrtf((float)d);
    l[t] = (i < N) ? d - 1 : 0;
    __syncthreads();
#pragma unroll
    for (int o = 1; o < 256; o <<= 1) {
        int u = (t >= o) ? l[t - o] : 0;
        __syncthreads();
        l[t] += u;
        __syncthreads();
    }
    if (i < N) tmp[i] = l[t];
    if (t == 255) bsum[blockIdx.x] = l[255];
}

__global__ __launch_bounds__(1024) void k_scan2(int* __restrict__ bsum, int nb) {
    __shared__ int l[1024];
    int t = threadIdx.x;
    l[t] = (t < nb) ? bsum[t] : 0;
    __syncthreads();
#pragma unroll
    for (int o = 1; o < 1024; o <<= 1) {
        int u = (t >= o) ? l[t - o] : 0;
        __syncthreads();
        l[t] += u;
        __syncthreads();
    }
    if (t < nb) bsum[t] = l[t];
}

__global__ __launch_bounds__(256) void k_scan3(const int* __restrict__ deg,
                                               const int* __restrict__ tmp,
                                               const int* __restrict__ bsum,
                                               int* __restrict__ row_ptr,
                                               int* __restrict__ cursor, int N, int E) {
    int i = blockIdx.x * 256 + threadIdx.x;
    if (i >= N) return;
    int excl = tmp[i] - (deg[i] - 1) + (blockIdx.x ? bsum[blockIdx.x - 1] : 0);
    row_ptr[i] = excl;
    cursor[i] = excl;
    if (i == 0) row_ptr[N] = E;
}

// XCD-routed CSR scatter with packed (col, wgt) records.
__global__ __launch_bounds__(256) void k_csr(const int* __restrict__ ei,
                                             const float* __restrict__ dinv,
                                             int* __restrict__ cursor,
                                             int2* __restrict__ erec, int E) {
    int tile = blockIdx.x >> 3;
    int cls  = blockIdx.x & 7;
    int base = tile * RTILE;
    int lim  = min(base + RTILE, E);
    for (int i = base + threadIdx.x; i < lim; i += 256) {
        int r = ei[i];
        if (((r >> 5) & 7) != cls) continue;
        int c = ei[E + i];
        int pos = atomicAdd(&cursor[r], 1);
        float w = dinv[r] * dinv[c];
        erec[pos] = make_int2(c, __float_as_int(w));
    }
}

// T[N,128](bf16) = X[N,128] @ W1. 32 nodes/block; thread: 4 nodes x 1 float4-col.
__global__ __launch_bounds__(256) void k_gemm1(const float* __restrict__ x,
                                               const float* __restrict__ W,
                                               unsigned* __restrict__ Tb, int N) {
    __shared__ float Wl[128 * 128];
    __shared__ float xl[32 * 128];
    int t = threadIdx.x;
    float4* Wl4 = (float4*)Wl;
    const float4* W4 = (const float4*)W;
#pragma unroll
    for (int i = 0; i < 16; ++i) Wl4[t + 256 * i] = W4[t + 256 * i];
    long long nbase = (long long)blockIdx.x * 32;
    float4* xl4 = (float4*)xl;
    const float4* x4 = (const float4*)x;
#pragma unroll
    for (int i = 0; i < 4; ++i) {
        int idx = t + 256 * i;
        long long n = nbase + idx / 32;
        if (n >= N) n = N - 1;
        xl4[idx] = x4[n * 32 + (idx & 31)];
    }
    __syncthreads();

    int fq = t & 31;
    int ng = t >> 5;
    float4 acc[4];
#pragma unroll
    for (int i = 0; i < 4; ++i) acc[i] = make_float4(0.f, 0.f, 0.f, 0.f);

#pragma unroll 8
    for (int k = 0; k < 128; ++k) {
        float4 w = Wl4[k * 32 + fq];
#pragma unroll
        for (int i = 0; i < 4; ++i) {
            float xv = xl[(ng + 8 * i) * 128 + k];
            acc[i].x = fmaf(xv, w.x, acc[i].x);
            acc[i].y = fmaf(xv, w.y, acc[i].y);
            acc[i].z = fmaf(xv, w.z, acc[i].z);
            acc[i].w = fmaf(xv, w.w, acc[i].w);
        }
    }
    uint2* T2 = (uint2*)Tb;
#pragma unroll
    for (int i = 0; i < 4; ++i) {
        long long n = nbase + ng + 8 * i;
        if (n < N) {
            uint2 o;
            o.x = pack2(acc[i].x, acc[i].y);
            o.y = pack2(acc[i].z, acc[i].w);
            T2[n * 32 + fq] = o;
        }
    }
}

// U[n](bf16) = relu( dinv^2*T[n] + sum_e w_e*T[col_e] + b1 )
// 16 lanes/node, 8 bf16 features per lane (uint4).
__global__ __launch_bounds__(256) void k_pull1(const uint4* __restrict__ Tb,
                                               const float* __restrict__ dinv,
                                               const int* __restrict__ row_ptr,
                                               const int2* __restrict__ erec,
                                               const float* __restrict__ b,
                                               uint4* __restrict__ Ub, int N) {
    int tid = blockIdx.x * 256 + threadIdx.x;
    int n = tid >> 4;
    if (n >= N) return;
    int q = tid & 15;

    float ss = dinv[n];
    ss = ss * ss;
    f8 s8 = unpack8(Tb[(size_t)n * 16 + q]);
    float acc[8];
#pragma unroll
    for (int j = 0; j < 8; ++j) acc[j] = s8.v[j] * ss;

    int beg = row_ptr[n], end = row_ptr[n + 1];
    int i = beg;
    for (; i + 1 < end; i += 2) {
        int2 e0 = erec[i];
        int2 e1 = erec[i + 1];
        float w0 = __int_as_float(e0.y);
        float w1 = __int_as_float(e1.y);
        uint4 g0 = Tb[(size_t)e0.x * 16 + q];
        uint4 g1 = Tb[(size_t)e1.x * 16 + q];
        f8 a0 = unpack8(g0);
        f8 a1 = unpack8(g1);
#pragma unroll
        for (int j = 0; j < 8; ++j) acc[j] = fmaf(w0, a0.v[j], acc[j]);
#pragma unroll
        for (int j = 0; j < 8; ++j) acc[j] = fmaf(w1, a1.v[j], acc[j]);
    }
    if (i < end) {
        int2 e0 = erec[i];
        float w0 = __int_as_float(e0.y);
        f8 a0 = unpack8(Tb[(size_t)e0.x * 16 + q]);
#pragma unroll
        for (int j = 0; j < 8; ++j) acc[j] = fmaf(w0, a0.v[j], acc[j]);
    }

    float4 b0 = ((const float4*)b)[q * 2];
    float4 b1v = ((const float4*)b)[q * 2 + 1];
    acc[0] = fmaxf(acc[0] + b0.x, 0.f);
    acc[1] = fmaxf(acc[1] + b0.y, 0.f);
    acc[2] = fmaxf(acc[2] + b0.z, 0.f);
    acc[3] = fmaxf(acc[3] + b0.w, 0.f);
    acc[4] = fmaxf(acc[4] + b1v.x, 0.f);
    acc[5] = fmaxf(acc[5] + b1v.y, 0.f);
    acc[6] = fmaxf(acc[6] + b1v.z, 0.f);
    acc[7] = fmaxf(acc[7] + b1v.w, 0.f);

    uint4 o;
    o.x = pack2(acc[0], acc[1]);
    o.y = pack2(acc[2], acc[3]);
    o.z = pack2(acc[4], acc[5]);
    o.w = pack2(acc[6], acc[7]);
    Ub[(size_t)n * 16 + q] = o;
}

// H2[N,40](bf16) = U[N,128](bf16) @ W2[128,40]. One thread: 2 nodes x 40 classes.
__global__ __launch_bounds__(256) void k_gemm2(const uint4* __restrict__ Ub,
                                               const float* __restrict__ W2,
                                               uint4* __restrict__ H2b, int N) {
    __shared__ float Wl[128 * 40];
    int t = threadIdx.x;
    float4* Wl4 = (float4*)Wl;
    const float4* W4 = (const float4*)W2;
#pragma unroll
    for (int i = 0; i < 5; ++i) Wl4[t + 256 * i] = W4[t + 256 * i];
    __syncthreads();

    int n0 = blockIdx.x * 512 + t;
    int n1 = n0 + 256;
    int n0c = n0 < N ? n0 : N - 1;
    int n1c = n1 < N ? n1 : N - 1;
    float a0[40], a1[40];
#pragma unroll
    for (int c = 0; c < 40; ++c) { a0[c] = 0.f; a1[c] = 0.f; }

    for (int k8 = 0; k8 < 16; ++k8) {
        f8 xa = unpack8(Ub[(size_t)n0c * 16 + k8]);
        f8 xb = unpack8(Ub[(size_t)n1c * 16 + k8]);
#pragma unroll
        for (int j = 0; j < 8; ++j) {
            float xaj = xa.v[j];
            float xbj = xb.v[j];
            int k = k8 * 8 + j;
#pragma unroll
            for (int cq = 0; cq < 10; ++cq) {
                float4 w = Wl4[k * 10 + cq];
                a0[cq * 4 + 0] = fmaf(xaj, w.x, a0[cq * 4 + 0]);
                a0[cq * 4 + 1] = fmaf(xaj, w.y, a0[cq * 4 + 1]);
                a0[cq * 4 + 2] = fmaf(xaj, w.z, a0[cq * 4 + 2]);
                a0[cq * 4 + 3] = fmaf(xaj, w.w, a0[cq * 4 + 3]);
                a1[cq * 4 + 0] = fmaf(xbj, w.x, a1[cq * 4 + 0]);
                a1[cq * 4 + 1] = fmaf(xbj, w.y, a1[cq * 4 + 1]);
                a1[cq * 4 + 2] = fmaf(xbj, w.z, a1[cq * 4 + 2]);
                a1[cq * 4 + 3] = fmaf(xbj, w.w, a1[cq * 4 + 3]);
            }
        }
    }
    if (n0 < N) {
#pragma unroll
        for (int g = 0; g < 5; ++g) {
            uint4 o;
            o.x = pack2(a0[g * 8 + 0], a0[g * 8 + 1]);
            o.y = pack2(a0[g * 8 + 2], a0[g * 8 + 3]);
            o.z = pack2(a0[g * 8 + 4], a0[g * 8 + 5]);
            o.w = pack2(a0[g * 8 + 6], a0[g * 8 + 7]);
            H2b[(size_t)n0 * 5 + g] = o;
        }
    }
    if (n1 < N) {
#pragma unroll
        for (int g = 0; g < 5; ++g) {
            uint4 o;
            o.x = pack2(a1[g * 8 + 0], a1[g * 8 + 1]);
            o.y = pack2(a1[g * 8 + 2], a1[g * 8 + 3]);
            o.z = pack2(a1[g * 8 + 4], a1[g * 8 + 5]);
            o.w = pack2(a1[g * 8 + 6], a1[g * 8 + 7]);
            H2b[(size_t)n1 * 5 + g] = o;
        }
    }
}

// out[n] = log_softmax( dinv^2*H2[n] + sum w*H2[c] + b2 )  (f32 out)
// 8 lanes/node; lanes q<5 hold 8 classes each (uint4 of bf16).
__global__ __launch_bounds__(256) void k_pull2(const uint4* __restrict__ H2b,
                                               const float* __restrict__ dinv,
                                               const int* __restrict__ row_ptr,
                                               const int2* __restrict__ erec,
                                               const float* __restrict__ b2,
                                               float* __restrict__ out, int N) {
    int tid = blockIdx.x * 256 + threadIdx.x;
    int n = tid >> 3;
    if (n >= N) return;
    int q = tid & 7;
    bool act = q < 5;

    float ss = dinv[n];
    ss = ss * ss;
    float acc[8];
#pragma unroll
    for (int j = 0; j < 8; ++j) acc[j] = 0.f;
    if (act) {
        f8 s8 = unpack8(H2b[(size_t)n * 5 + q]);
#pragma unroll
        for (int j = 0; j < 8; ++j) acc[j] = s8.v[j] * ss;
    }
    int beg = row_ptr[n], end = row_ptr[n + 1];
    for (int i = beg; i < end; ++i) {
        int2 e = erec[i];
        if (act) {
            float w = __int_as_float(e.y);
            f8 a = unpack8(H2b[(size_t)e.x * 5 + q]);
#pragma unroll
            for (int j = 0; j < 8; ++j) acc[j] = fmaf(w, a.v[j], acc[j]);
        }
    }
    if (act) {
        float4 b0 = ((const float4*)b2)[q * 2];
        float4 b1v = ((const float4*)b2)[q * 2 + 1];
        acc[0] += b0.x; acc[1] += b0.y; acc[2] += b0.z; acc[3] += b0.w;
        acc[4] += b1v.x; acc[5] += b1v.y; acc[6] += b1v.z; acc[7] += b1v.w;
    }
    float m = -INFINITY;
    if (act) {
#pragma unroll
        for (int j = 0; j < 8; ++j) m = fmaxf(m, acc[j]);
    }
#pragma unroll
    for (int o = 4; o > 0; o >>= 1) m = fmaxf(m, __shfl_xor(m, o, 8));
    float e = 0.f;
    if (act) {
#pragma unroll
        for (int j = 0; j < 8; ++j) e += expf(acc[j] - m);
    }
#pragma unroll
    for (int o = 4; o > 0; o >>= 1) e += __shfl_xor(e, o, 8);
    float lg = m + logf(e);
    if (act) {
        float4* o4 = (float4*)out;
        o4[(size_t)n * 10 + q * 2] =
            make_float4(acc[0] - lg, acc[1] - lg, acc[2] - lg, acc[3] - lg);
        o4[(size_t)n * 10 + q * 2 + 1] =
            make_float4(acc[4] - lg, acc[5] - lg, acc[6] - lg, acc[7] - lg);
    }
}

extern "C" void kernel_launch(void* const* d_in, const int* in_sizes, int n_in,
                              void* d_out, int out_size, void* d_ws, size_t ws_size,
                              hipStream_t stream) {
    const float* x  = (const float*)d_in[0];
    const int*   ei = (const int*)d_in[1];   // integer inputs arrive as int32
    const float* W1 = (const float*)d_in[2];
    const float* b1 = (const float*)d_in[3];
    const float* W2 = (const float*)d_in[4];
    const float* b2 = (const float*)d_in[5];
    float* out = (float*)d_out;

    const int N = in_sizes[0] / 128;  // 100000
    const int E = in_sizes[1] / 2;    // 1600000

    // workspace layout (~76 MB)
    char* ws = (char*)d_ws;
    int*   deg     = (int*)(ws);
    float* dinv    = (float*)(ws + (512 << 10));
    int*   row_ptr = (int*)(ws + (1 << 20));
    int*   cursor  = (int*)(ws + (1536 << 10));
    int*   bsum    = (int*)(ws + (2 << 20));
    int*   tmp     = (int*)(ws + (2 << 20) + (128 << 10));
    int2*  erec    = (int2*)(ws + (3 << 20));          // E int2 = 12.8 MB
    uint4* H2b     = (uint4*)(ws + (16 << 20));        // N*40 bf16 = 8 MB
    unsigned* Tb   = (unsigned*)(ws + (24 << 20));     // N*128 bf16 = 25.6 MB
    uint4* Ub      = (uint4*)(ws + (50 << 20));        // N*128 bf16 = 25.6 MB

    int nb = (N + 255) / 256;
    int rblocks = ((E + RTILE - 1) / RTILE) * 8;  // 8 class-blocks per tile

    k_init_deg<<<nb, 256, 0, stream>>>(deg, N);
    k_count<<<rblocks, 256, 0, stream>>>(ei, deg, E);
    k_scan1<<<nb, 256, 0, stream>>>(deg, tmp, bsum, dinv, N);
    k_scan2<<<1, 1024, 0, stream>>>(bsum, nb);
    k_scan3<<<nb, 256, 0, stream>>>(deg, tmp, bsum, row_ptr, cursor, N, E);
    k_csr<<<rblocks, 256, 0, stream>>>(ei, dinv, cursor, erec, E);

    k_gemm1<<<(N + 31) / 32, 256, 0, stream>>>(x, W1, Tb, N);
    k_pull1<<<((long long)N * 16 + 255) / 256, 256, 0, stream>>>(
        (const uint4*)Tb, dinv, row_ptr, erec, b1, Ub, N);
    k_gemm2<<<(N + 511) / 512, 256, 0, stream>>>(Ub, W2, H2b, N);
    k_pull2<<<((long long)N * 8 + 255) / 256, 256, 0, stream>>>(
        H2b, dinv, row_ptr, erec, b2, out, N);
}